// Round 5
// baseline (268.147 us; speedup 1.0000x reference)
//
#include <hip/hip_runtime.h>
#include <hip/hip_bf16.h>
#include <stdint.h>

#define SEQ    2048
#define NBATCH 4
#define NHEADS 16
#define DHEAD  64
#define MODELD 1024
#define QKVN   1152          // 1024 q + 64 k + 64 v columns
#define MROWS  (NBATCH*SEQ)  // 8192
// exp(s*0.125) == exp2(s * 0.125 * log2(e)); folded into w_q at transpose time
#define SCALE_LOG2E 0.1803368801111244f

typedef __bf16 bf16x8 __attribute__((ext_vector_type(8)));
typedef float  f32x4  __attribute__((ext_vector_type(4)));

typedef __attribute__((address_space(1))) void* as1_void_p;
typedef __attribute__((address_space(3))) void* as3_void_p;

__device__ __forceinline__ void gld_lds16(const void* g, void* l) {
  __builtin_amdgcn_global_load_lds((as1_void_p)(g), (as3_void_p)(l), 16, 0, 0);
}

__device__ __forceinline__ ushort f2bf(float f) {
  union { float f; uint32_t i; } t; t.f = f;
  uint32_t r = (t.i + 0x7fffu + ((t.i >> 16) & 1u)) >> 16;
  return (ushort)r;
}
__device__ __forceinline__ uint32_t pack_bf16(float a, float b) {
  union { __hip_bfloat162 h2; uint32_t u; } cv;
  cv.h2 = __float22bfloat162_rn(make_float2(a, b));
  return cv.u;
}

// ---------------- fused prep: x convert + 3 weight transposes ----------------
// flat grid: [0,8192) x-convert; [8192,9216) w_q^T; [9216,9344) w_kv^T; [9344,10368) w_out^T
__device__ __forceinline__ void do_transpose(const float* __restrict__ src,
                                             ushort* __restrict__ dst,
                                             int R, int C, float scale,
                                             int gx, int gy, int tid) {
  __shared__ float tile[32][33];
  const int tx = tid & 31, ty = tid >> 5;  // ty in 0..7
  const int c0 = gx * 32, r0 = gy * 32;
#pragma unroll
  for (int j = 0; j < 4; j++)
    tile[ty*4 + j][tx] = src[(size_t)(r0 + ty*4 + j) * C + c0 + tx];
  __syncthreads();
#pragma unroll
  for (int j = 0; j < 4; j++)
    dst[(size_t)(c0 + ty*4 + j) * R + r0 + tx] = f2bf(tile[tx][ty*4 + j] * scale);
}

__global__ __launch_bounds__(256)
void prep(const float* __restrict__ x, const float* __restrict__ w_q,
          const float* __restrict__ w_kv, const float* __restrict__ w_out,
          ushort* __restrict__ xb, ushort* __restrict__ wqkvT,
          ushort* __restrict__ woutT) {
  const int bid = blockIdx.x, tid = threadIdx.x;
  if (bid < 8192) {                      // x -> bf16, 1024 elems/block
    const size_t i = ((size_t)bid * 256 + tid) * 4;
    const float4 v = *(const float4*)(x + i);
    ushort4 o;
    o.x = f2bf(v.x); o.y = f2bf(v.y); o.z = f2bf(v.z); o.w = f2bf(v.w);
    *(ushort4*)(xb + i) = o;
  } else if (bid < 9216) {               // w_q^T (scale folded)
    const int t = bid - 8192;
    do_transpose(w_q, wqkvT, MODELD, MODELD, SCALE_LOG2E, t & 31, t >> 5, tid);
  } else if (bid < 9344) {               // w_kv^T -> rows 1024..1151
    const int t = bid - 9216;
    do_transpose(w_kv, wqkvT + (size_t)MODELD * MODELD, MODELD, 128, 1.0f,
                 t & 3, t >> 2, tid);
  } else {                               // w_out^T
    const int t = bid - 9344;
    do_transpose(w_out, woutT, MODELD, MODELD, 1.0f, t & 31, t >> 5, tid);
  }
}

// ---------------- GEMM: C(MxN) = A(MxK) * Bt(NxK)^T  (+bias), bf16 in --------
// m97 structure: 128x128 tile, BK=32, 4 waves, global_load_lds width-16 staging.
// T1 (m204): bijective XCD-aware tile remap (verified R4: total -5.2us, modest —
// GEMMs are staging/barrier-bound, not fetch-bound at K=1024).
// VT!=nullptr: additionally write cols 1088..1151 transposed as vT[b][d][n] (bf16).
template <bool OUT_F32>
__global__ __launch_bounds__(256)
void gemm_bt(const ushort* __restrict__ A, const ushort* __restrict__ Bt,
             void* __restrict__ Cp, const float* __restrict__ bias,
             ushort* __restrict__ VT,
             int K, int lda, int ldb, int ldc) {
  __shared__ __attribute__((aligned(16))) ushort As[128*32];
  __shared__ __attribute__((aligned(16))) ushort Bs[128*32];
  const int tid = threadIdx.x;
  const int w = tid >> 6, lane = tid & 63;
  const int quad = lane >> 4, m16 = lane & 15;

  // bijective XCD swizzle (m204): phys id -> contiguous logical chunk per XCD
  const int nwg = gridDim.x * gridDim.y;
  const int orig = blockIdx.y * gridDim.x + blockIdx.x;
  const int qq = nwg >> 3, rr = nwg & 7;
  const int xcd = orig & 7, loc = orig >> 3;
  const int L = (xcd < rr ? xcd * (qq + 1) : rr * (qq + 1) + (xcd - rr) * qq) + loc;
  const int bm0 = (L / gridDim.x) * 128, bn0 = (L % gridDim.x) * 128;

  f32x4 acc[4][4] = {};

  const int ar0 = w*32 + (lane >> 2);
  const int ac0 = (lane & 3) * 8;
  const ushort* Ag = A  + (size_t)(bm0 + ar0) * lda + ac0;
  const ushort* Bg = Bt + (size_t)(bn0 + ar0) * ldb + ac0;
  ushort* AsW = As + (w*32)*32;   // wave-uniform base; HW adds lane*16B
  ushort* BsW = Bs + (w*32)*32;
  const int wm = (w >> 1) * 64, wn = (w & 1) * 64;

  for (int kb = 0; kb < K; kb += 32) {
    gld_lds16(Ag + kb,                   AsW);
    gld_lds16(Ag + (size_t)16*lda + kb,  AsW + 16*32);
    gld_lds16(Bg + kb,                   BsW);
    gld_lds16(Bg + (size_t)16*ldb + kb,  BsW + 16*32);
    __syncthreads();
    bf16x8 af[4], bfr[4];
#pragma unroll
    for (int mi = 0; mi < 4; mi++)
      af[mi] = *(const bf16x8*)(As + (wm + mi*16 + m16)*32 + quad*8);
#pragma unroll
    for (int ni = 0; ni < 4; ni++)
      bfr[ni] = *(const bf16x8*)(Bs + (wn + ni*16 + m16)*32 + quad*8);
#pragma unroll
    for (int mi = 0; mi < 4; mi++)
#pragma unroll
      for (int ni = 0; ni < 4; ni++)
        acc[mi][ni] = __builtin_amdgcn_mfma_f32_16x16x32_bf16(
            af[mi], bfr[ni], acc[mi][ni], 0, 0, 0);
    __syncthreads();
  }

  // epilogue: C/D layout col=lane&15, row=quad*4+reg
  const bool blockHasV = (VT != nullptr) && (bn0 + 128 > 1088);
#pragma unroll
  for (int ni = 0; ni < 4; ni++) {
    const int col = bn0 + wn + ni*16 + m16;
    const float bv = bias ? bias[col] : 0.0f;
#pragma unroll
    for (int mi = 0; mi < 4; mi++) {
#pragma unroll
      for (int r = 0; r < 4; r++) {
        const int row = bm0 + wm + mi*16 + quad*4 + r;
        const float v = acc[mi][ni][r] + bv;
        if (OUT_F32) ((float*)Cp)[(size_t)row*ldc + col] = v;
        else         ((ushort*)Cp)[(size_t)row*ldc + col] = f2bf(v);
        if (blockHasV && col >= 1088) {  // V columns -> transposed copy
          const int d = col - 1088, bb = row >> 11, n = row & 2047;
          VT[((size_t)bb * DHEAD + d) * SEQ + n] = f2bf(v);
        }
      }
    }
  }
}

// ---------------- Flash MQA attention, v8 (butterfly; R2-audited) ----------
// grid (SEQ/128, NHEADS, NBATCH) = 1024 blocks, 256 threads = 4 waves,
// 32 Q rows per wave. KV chunk 64.
// v8 vs v7: P redistribution QK-layout -> PV-B-layout fully in registers via a
// 2-stage butterfly (shfl_xor 32 then 16) within quad groups. Removes pbuf
// (18.4 KB), 20 LDS ops/wave-chunk, and the per-chunk lgkmcnt(0) drain -> the
// chunk body is pure register dataflow between staging barriers, so QK-VALU
// and PV-MFMA co-schedule. Numerics bit-identical to v7 (R4-verified).
// R2/R3 container failures attributed to infra (R4: identical-attn source
// passed on same-degraded harness).
// LDS 20.7 KB, ~100 VGPR -> 4 blocks/CU (grid-matched).
__global__ __launch_bounds__(256, 2)
void mqa_attn(const ushort* __restrict__ qkv, const ushort* __restrict__ vT,
              ushort* __restrict__ attn_out) {
  __shared__ __attribute__((aligned(16))) ushort Ks[64*72];      // K[kv][d], pad 72
  __shared__ __attribute__((aligned(16))) ushort Vs[80*72];      // V^T[d][kv]; rows 64..79 = ones-tile

  const int tid = threadIdx.x;
  const int w = tid >> 6, lane = tid & 63;
  const int quad = lane >> 4, m16 = lane & 15;
  const bool hb = (lane & 32) != 0;   // quad bit1
  const bool lb = (lane & 16) != 0;   // quad bit0
  const int h = blockIdx.y, b = blockIdx.z;
  const size_t rowbase = (size_t)b * SEQ;
  const int q0 = blockIdx.x * 128 + w * 32;
  const ushort* vTb = vT + (size_t)b * DHEAD * SEQ;

  // ones-tile init (once): Vs row 64 = 1.0 (bf16 0x3F80), rows 65..79 = 0.
  // Staging never touches rows >= 64; visible after the first staging barrier.
  for (int i = tid; i < 16*72; i += 256)
    Vs[64*72 + i] = (i < 72) ? (ushort)0x3F80 : (ushort)0;

  // staging map: thread covers (row = tid>>3, col = (tid&7)*8), 2 passes of 32 rows
  const int srow = tid >> 3, scol = (tid & 7) * 8;
  const ushort* kgbase = qkv + (rowbase + srow) * QKVN + 1024 + scol;
  const ushort* vgbase = vTb + (size_t)srow * SEQ + scol;

  // persistent Q fragments (B-layout: n=q=m16, k=d=kh*32+quad*8); q pre-scaled
  bf16x8 qf[2][2];
#pragma unroll
  for (int qt = 0; qt < 2; qt++) {
    const ushort* qrow = qkv + (rowbase + q0 + qt*16 + m16) * QKVN + h * DHEAD;
    qf[qt][0] = *(const bf16x8*)(qrow + quad*8);
    qf[qt][1] = *(const bf16x8*)(qrow + 32 + quad*8);
  }

  f32x4 o[2][4] = {};   // O^T tiles [qt][dt], C-layout: row=d=quad*4+r, col=q=m16
  f32x4 o4[2]   = {};   // l-tile: ones-row MFMA accumulator; sum at quad==0, r==0

  // preload chunk 0
  uint4 kreg0 = *(const uint4*)(kgbase);
  uint4 kreg1 = *(const uint4*)(kgbase + (size_t)32 * QKVN);
  uint4 vreg0 = *(const uint4*)(vgbase);
  uint4 vreg1 = *(const uint4*)(vgbase + 32 * SEQ);

  for (int kv0 = 0; kv0 < SEQ; kv0 += 64) {
    __syncthreads();                         // prev chunk's readers done
    *(uint4*)(Ks + (srow     )*72 + scol) = kreg0;
    *(uint4*)(Ks + (srow + 32)*72 + scol) = kreg1;
    *(uint4*)(Vs + (srow     )*72 + scol) = vreg0;
    *(uint4*)(Vs + (srow + 32)*72 + scol) = vreg1;
    __syncthreads();                         // staging (+ ones-tile) visible

    // issue NEXT chunk's global loads now (latency hidden behind this chunk)
    const int kvn = (kv0 + 64) & (SEQ - 1);
    kreg0 = *(const uint4*)(kgbase + (size_t)(kvn     ) * QKVN);
    kreg1 = *(const uint4*)(kgbase + (size_t)(kvn + 32) * QKVN);
    vreg0 = *(const uint4*)(vgbase + kvn);
    vreg1 = *(const uint4*)(vgbase + 32 * SEQ + kvn);

    // ---- S^T = K Q^T for all 64 kv; p = exp2(s); pack to bf16 pairs in regs ----
    // w[qt][t][i]: lane (quad,m16) holds P[kv = t*16 + quad*4 + 2i+{0,1}][q=qt*16+m16]
    uint32_t wreg[2][4][2];
#pragma unroll
    for (int t = 0; t < 4; t++) {
      const bf16x8 kf0 = *(const bf16x8*)(Ks + (t*16 + m16)*72 + quad*8);
      const bf16x8 kf1 = *(const bf16x8*)(Ks + (t*16 + m16)*72 + 32 + quad*8);
#pragma unroll
      for (int qt = 0; qt < 2; qt++) {
        f32x4 s = {};
        s = __builtin_amdgcn_mfma_f32_16x16x32_bf16(kf0, qf[qt][0], s, 0, 0, 0);
        s = __builtin_amdgcn_mfma_f32_16x16x32_bf16(kf1, qf[qt][1], s, 0, 0, 0);
        float p[4];
#pragma unroll
        for (int r = 0; r < 4; r++)
          p[r] = __builtin_amdgcn_exp2f(s[r]);   // kv=t*16+quad*4+r, q=m16
        wreg[qt][t][0] = pack_bf16(p[0], p[1]);
        wreg[qt][t][1] = pack_bf16(p[2], p[3]);
      }
    }

    // ---- per 32-kv half: in-register butterfly -> pf (PV B-operand), then PV ----
    // Target: lane (quad,m16) needs P[kv = kh*32 + quad*8 + j][q], j=0..7.
    // Dest (hb,lb) needs tile(hb) rows of source quads (bit1=lb,bit0=0) -> dw0,1
    // and (bit1=lb,bit0=1) -> dw2,3.
    // Stage 1 (xor 32): send tile(!hb), keep k=tile(hb) -> k:(hb,lb), r:(!hb,lb).
    // Stage 2 (xor 16): send (lb!=hb)?k:r, keep e=(lb==hb)?k:r; receive s.
    // All 4 (hb,lb) cases enumerate to: lb==0 -> pf={e0,e1,s0,s1}; lb==1 ->
    // pf={s0,s1,e0,e1}, with kv ordering j=0..7 correct. (R1+R2 audits.)
#pragma unroll
    for (int kh = 0; kh < 2; kh++) {
      bf16x8 pfr[2], vf[4], vf4;
#pragma unroll
      for (int qt = 0; qt < 2; qt++) {
        const uint32_t a0 = wreg[qt][kh*2][0],   a1 = wreg[qt][kh*2][1];
        const uint32_t b0 = wreg[qt][kh*2+1][0], b1 = wreg[qt][kh*2+1][1];
        const uint32_t u0 = hb ? a0 : b0,  u1 = hb ? a1 : b1;
        const uint32_t r0 = __shfl_xor(u0, 32), r1 = __shfl_xor(u1, 32);
        const uint32_t k0 = hb ? b0 : a0,  k1 = hb ? b1 : a1;
        const uint32_t v0 = (lb != hb) ? k0 : r0, v1 = (lb != hb) ? k1 : r1;
        const uint32_t s0 = __shfl_xor(v0, 16), s1 = __shfl_xor(v1, 16);
        const uint32_t e0 = (lb == hb) ? k0 : r0, e1 = (lb == hb) ? k1 : r1;
        union { uint32_t u[4]; bf16x8 v; } cv;
        cv.u[0] = lb ? s0 : e0;  cv.u[1] = lb ? s1 : e1;
        cv.u[2] = lb ? e0 : s0;  cv.u[3] = lb ? e1 : s1;
        pfr[qt] = cv.v;
      }
#pragma unroll
      for (int dt = 0; dt < 4; dt++)
        vf[dt] = *(const bf16x8*)(Vs + (dt*16 + m16)*72 + kh*32 + quad*8);
      vf4 = *(const bf16x8*)(Vs + (64 + m16)*72 + kh*32 + quad*8);
      __builtin_amdgcn_s_setprio(1);
#pragma unroll
      for (int qt = 0; qt < 2; qt++) {
#pragma unroll
        for (int dt = 0; dt < 4; dt++)
          o[qt][dt] = __builtin_amdgcn_mfma_f32_16x16x32_bf16(vf[dt], pfr[qt], o[qt][dt], 0, 0, 0);
        o4[qt] = __builtin_amdgcn_mfma_f32_16x16x32_bf16(vf4, pfr[qt], o4[qt], 0, 0, 0);
      }
      __builtin_amdgcn_s_setprio(0);
    }
  }

  // ---- epilogue: l = o4[qt][0] at lane m16 (quad 0, r 0); broadcast, divide ----
#pragma unroll
  for (int qt = 0; qt < 2; qt++) {
    const float l = __shfl(o4[qt][0], m16, 64);  // every lane reads its q=m16 sum
    const float inv = 1.0f / l;
    const size_t row = rowbase + q0 + qt*16 + m16;     // q = m16
#pragma unroll
    for (int dt = 0; dt < 4; dt++) {
      ushort4 st;
      st.x = f2bf(o[qt][dt][0] * inv);
      st.y = f2bf(o[qt][dt][1] * inv);
      st.z = f2bf(o[qt][dt][2] * inv);
      st.w = f2bf(o[qt][dt][3] * inv);
      *(ushort4*)(attn_out + row*MODELD + h*DHEAD + dt*16 + quad*4) = st;
    }
  }
}

// ---------------- launch ----------------
extern "C" void kernel_launch(void* const* d_in, const int* in_sizes, int n_in,
                              void* d_out, int out_size, void* d_ws, size_t ws_size,
                              hipStream_t stream) {
  // Reference dtypes: ALL inputs fp32, output fp32.
  const float* x     = (const float*)d_in[0];
  const float* w_q   = (const float*)d_in[1];
  const float* w_kv  = (const float*)d_in[2];
  const float* w_out = (const float*)d_in[3];
  const float* b_out = (const float*)d_in[4];

  ushort* wqkvT = (ushort*)d_ws;                         // 1152 x 1024 bf16
  ushort* woutT = wqkvT + (size_t)QKVN * MODELD;         // 1024 x 1024 bf16
  ushort* xb    = woutT + (size_t)MODELD * MODELD;       // 8192 x 1024 bf16
  ushort* qkv   = xb    + (size_t)MROWS * MODELD;        // 8192 x 1152 bf16
  ushort* attn  = qkv   + (size_t)MROWS * QKVN;          // 8192 x 1024 bf16
  ushort* vTb   = attn  + (size_t)MROWS * MODELD;        // 4 x 64 x 2048 bf16 (V^T)
  // total ws use ~59 MB

  // fused prep: x->bf16 + 3 weight transposes (scale folded into w_q)
  prep<<<10368, 256, 0, stream>>>(x, w_q, w_kv, w_out, xb, wqkvT, woutT);

  // fused QKV projection: (8192x1024) @ (1152x1024)^T -> 8192x1152 bf16 (+ V^T side-write)
  gemm_bt<false><<<dim3(QKVN/128, MROWS/128), 256, 0, stream>>>(
      xb, wqkvT, (void*)qkv, nullptr, vTb, MODELD, MODELD, MODELD, QKVN);

  // flash MQA -> attn (8192 x 1024 bf16, col = h*64+d)
  mqa_attn<<<dim3(SEQ/128, NHEADS, NBATCH), 256, 0, stream>>>(qkv, vTb, attn);

  // output projection + bias -> d_out (fp32)
  gemm_bt<true><<<dim3(MODELD/128, MROWS/128), 256, 0, stream>>>(
      attn, woutT, d_out, b_out, nullptr, MODELD, MODELD, MODELD, MODELD);
}

// Round 6
// 248.552 us; speedup vs baseline: 1.0788x; 1.0788x over previous
//
#include <hip/hip_runtime.h>
#include <hip/hip_bf16.h>
#include <stdint.h>

#define SEQ    2048
#define NBATCH 4
#define NHEADS 16
#define DHEAD  64
#define MODELD 1024
#define QKVN   1152          // 1024 q + 64 k + 64 v columns
#define MROWS  (NBATCH*SEQ)  // 8192
// exp(s*0.125) == exp2(s * 0.125 * log2(e)); folded into w_q at transpose time
#define SCALE_LOG2E 0.1803368801111244f

typedef __bf16 bf16x8 __attribute__((ext_vector_type(8)));
typedef float  f32x4  __attribute__((ext_vector_type(4)));

typedef __attribute__((address_space(1))) void* as1_void_p;
typedef __attribute__((address_space(3))) void* as3_void_p;

__device__ __forceinline__ void gld_lds16(const void* g, void* l) {
  __builtin_amdgcn_global_load_lds((as1_void_p)(g), (as3_void_p)(l), 16, 0, 0);
}

__device__ __forceinline__ ushort f2bf(float f) {
  union { float f; uint32_t i; } t; t.f = f;
  uint32_t r = (t.i + 0x7fffu + ((t.i >> 16) & 1u)) >> 16;
  return (ushort)r;
}
__device__ __forceinline__ uint32_t pack_bf16(float a, float b) {
  union { __hip_bfloat162 h2; uint32_t u; } cv;
  cv.h2 = __float22bfloat162_rn(make_float2(a, b));
  return cv.u;
}

// ---------------- fused prep: x convert + 3 weight transposes ----------------
// flat grid: [0,8192) x-convert; [8192,9216) w_q^T; [9216,9344) w_kv^T; [9344,10368) w_out^T
__device__ __forceinline__ void do_transpose(const float* __restrict__ src,
                                             ushort* __restrict__ dst,
                                             int R, int C, float scale,
                                             int gx, int gy, int tid) {
  __shared__ float tile[32][33];
  const int tx = tid & 31, ty = tid >> 5;  // ty in 0..7
  const int c0 = gx * 32, r0 = gy * 32;
#pragma unroll
  for (int j = 0; j < 4; j++)
    tile[ty*4 + j][tx] = src[(size_t)(r0 + ty*4 + j) * C + c0 + tx];
  __syncthreads();
#pragma unroll
  for (int j = 0; j < 4; j++)
    dst[(size_t)(c0 + ty*4 + j) * R + r0 + tx] = f2bf(tile[tx][ty*4 + j] * scale);
}

__global__ __launch_bounds__(256)
void prep(const float* __restrict__ x, const float* __restrict__ w_q,
          const float* __restrict__ w_kv, const float* __restrict__ w_out,
          ushort* __restrict__ xb, ushort* __restrict__ wqkvT,
          ushort* __restrict__ woutT) {
  const int bid = blockIdx.x, tid = threadIdx.x;
  if (bid < 8192) {                      // x -> bf16, 1024 elems/block
    const size_t i = ((size_t)bid * 256 + tid) * 4;
    const float4 v = *(const float4*)(x + i);
    ushort4 o;
    o.x = f2bf(v.x); o.y = f2bf(v.y); o.z = f2bf(v.z); o.w = f2bf(v.w);
    *(ushort4*)(xb + i) = o;
  } else if (bid < 9216) {               // w_q^T (scale folded)
    const int t = bid - 8192;
    do_transpose(w_q, wqkvT, MODELD, MODELD, SCALE_LOG2E, t & 31, t >> 5, tid);
  } else if (bid < 9344) {               // w_kv^T -> rows 1024..1151
    const int t = bid - 9216;
    do_transpose(w_kv, wqkvT + (size_t)MODELD * MODELD, MODELD, 128, 1.0f,
                 t & 3, t >> 2, tid);
  } else {                               // w_out^T
    const int t = bid - 9344;
    do_transpose(w_out, woutT, MODELD, MODELD, 1.0f, t & 31, t >> 5, tid);
  }
}

// ---------------- GEMM: C(MxN) = A(MxK) * Bt(NxK)^T  (+bias), bf16 in --------
// R5: BK 32->64 — halves per-block barrier-drain count (32->16 K-steps at
// K=1024) and doubles the MFMA cluster per phase (32 MFMA between barriers).
// LDS rows are now 128B -> pathological bank pattern, fixed by rule-#21
// both-sides XOR involution: linear LDS dest (gld_lds), global SOURCE granule
// pre-XOR'd with row&7, fragment reads XOR the same. row&7 == (lane>>3)&7 for
// all staging calls (row offsets are multiples of 8), so the source XOR is
// lane-static. MFMA accumulation order is bit-identical to BK=32.
// T1 (m204): bijective XCD-aware tile remap (R4: ~-3..5us).
// VT!=nullptr: additionally write cols 1088..1151 transposed as vT[b][d][n].
template <bool OUT_F32>
__global__ __launch_bounds__(256)
void gemm_bt(const ushort* __restrict__ A, const ushort* __restrict__ Bt,
             void* __restrict__ Cp, const float* __restrict__ bias,
             ushort* __restrict__ VT,
             int K, int lda, int ldb, int ldc) {
  __shared__ __attribute__((aligned(16))) ushort As[128*64];
  __shared__ __attribute__((aligned(16))) ushort Bs[128*64];
  const int tid = threadIdx.x;
  const int w = tid >> 6, lane = tid & 63;
  const int quad = lane >> 4, m16 = lane & 15;

  // bijective XCD swizzle (m204): phys id -> contiguous logical chunk per XCD
  const int nwg = gridDim.x * gridDim.y;
  const int orig = blockIdx.y * gridDim.x + blockIdx.x;
  const int qq = nwg >> 3, rr = nwg & 7;
  const int xcd = orig & 7, loc = orig >> 3;
  const int L = (xcd < rr ? xcd * (qq + 1) : rr * (qq + 1) + (xcd - rr) * qq) + loc;
  const int bm0 = (L / gridDim.x) * 128, bn0 = (L % gridDim.x) * 128;

  f32x4 acc[4][4] = {};

  // staging map: lane covers (row = w*32 + c*8 + (lane>>3), granule = lane&7),
  // 4 calls (c=0..3) per matrix. Source granule XOR'd (involution).
  const int sr = lane >> 3;                       // 0..7
  const int sg = ((lane & 7) ^ (sr & 7)) * 8;     // pre-swizzled source col
  const ushort* Ag = A  + (size_t)(bm0 + w*32 + sr) * lda + sg;
  const ushort* Bg = Bt + (size_t)(bn0 + w*32 + sr) * ldb + sg;
  ushort* AsW = As + (w*32)*64;   // wave-uniform base; HW adds lane*16B
  ushort* BsW = Bs + (w*32)*64;
  const int wm = (w >> 1) * 64, wn = (w & 1) * 64;

  for (int kb = 0; kb < K; kb += 64) {
#pragma unroll
    for (int c = 0; c < 4; c++) {
      gld_lds16(Ag + (size_t)(c*8)*lda + kb, AsW + c*8*64);
      gld_lds16(Bg + (size_t)(c*8)*ldb + kb, BsW + c*8*64);
    }
    __syncthreads();
#pragma unroll
    for (int kk = 0; kk < 2; kk++) {
      bf16x8 af[4], bfr[4];
      const int rg = ((kk*4 + quad) ^ (m16 & 7)) * 8;  // swizzled read granule
#pragma unroll
      for (int mi = 0; mi < 4; mi++)
        af[mi] = *(const bf16x8*)(As + (wm + mi*16 + m16)*64 + rg);
#pragma unroll
      for (int ni = 0; ni < 4; ni++)
        bfr[ni] = *(const bf16x8*)(Bs + (wn + ni*16 + m16)*64 + rg);
#pragma unroll
      for (int mi = 0; mi < 4; mi++)
#pragma unroll
        for (int ni = 0; ni < 4; ni++)
          acc[mi][ni] = __builtin_amdgcn_mfma_f32_16x16x32_bf16(
              af[mi], bfr[ni], acc[mi][ni], 0, 0, 0);
    }
    __syncthreads();
  }

  // epilogue: C/D layout col=lane&15, row=quad*4+reg
  const bool blockHasV = (VT != nullptr) && (bn0 + 128 > 1088);
#pragma unroll
  for (int ni = 0; ni < 4; ni++) {
    const int col = bn0 + wn + ni*16 + m16;
    const float bv = bias ? bias[col] : 0.0f;
#pragma unroll
    for (int mi = 0; mi < 4; mi++) {
#pragma unroll
      for (int r = 0; r < 4; r++) {
        const int row = bm0 + wm + mi*16 + quad*4 + r;
        const float v = acc[mi][ni][r] + bv;
        if (OUT_F32) ((float*)Cp)[(size_t)row*ldc + col] = v;
        else         ((ushort*)Cp)[(size_t)row*ldc + col] = f2bf(v);
        if (blockHasV && col >= 1088) {  // V columns -> transposed copy
          const int d = col - 1088, bb = row >> 11, n = row & 2047;
          VT[((size_t)bb * DHEAD + d) * SEQ + n] = f2bf(v);
        }
      }
    }
  }
}

// ---------------- Flash MQA attention, v7 (R4-verified; v8 butterfly reverted:
// +12% regression — shfl chain serialized exp->PV; conflicts were not on the
// critical path) ----------
// grid (SEQ/128, NHEADS, NBATCH) = 1024 blocks, 256 threads = 4 waves,
// 32 Q rows per wave. KV chunk 64.
//  (a) l = sum_kv p via MFMA ones-row tile (Vs rows 64..79).
//  (b) single lgkmcnt(0) drain per 64-kv chunk; per-wave pbuf 64 kv cols.
//  (c) T5 s_setprio(1) around PV MFMA clusters.
// LDS 38.3 KB -> 4 blocks/CU (grid-matched).
__global__ __launch_bounds__(256, 2)
void mqa_attn(const ushort* __restrict__ qkv, const ushort* __restrict__ vT,
              ushort* __restrict__ attn_out) {
  __shared__ __attribute__((aligned(16))) ushort Ks[64*72];      // K[kv][d], pad 72
  __shared__ __attribute__((aligned(16))) ushort Vs[80*72];      // V^T[d][kv]; rows 64..79 = ones-tile
  __shared__ __attribute__((aligned(16))) ushort pbuf[4][32*72]; // per-wave P[q(32)][64kv], pad 72

  const int tid = threadIdx.x;
  const int w = tid >> 6, lane = tid & 63;
  const int quad = lane >> 4, m16 = lane & 15;
  const int h = blockIdx.y, b = blockIdx.z;
  const size_t rowbase = (size_t)b * SEQ;
  const int q0 = blockIdx.x * 128 + w * 32;
  const ushort* vTb = vT + (size_t)b * DHEAD * SEQ;
  ushort* pb = pbuf[w];

  // ones-tile init (once): Vs row 64 = 1.0 (bf16 0x3F80), rows 65..79 = 0.
  // Staging never touches rows >= 64; visible after the first staging barrier.
  for (int i = tid; i < 16*72; i += 256)
    Vs[64*72 + i] = (i < 72) ? (ushort)0x3F80 : (ushort)0;

  // staging map: thread covers (row = tid>>3, col = (tid&7)*8), 2 passes of 32 rows
  const int srow = tid >> 3, scol = (tid & 7) * 8;
  const ushort* kgbase = qkv + (rowbase + srow) * QKVN + 1024 + scol;
  const ushort* vgbase = vTb + (size_t)srow * SEQ + scol;

  // persistent Q fragments (B-layout: n=q=m16, k=d=kh*32+quad*8); q pre-scaled
  bf16x8 qf[2][2];
#pragma unroll
  for (int qt = 0; qt < 2; qt++) {
    const ushort* qrow = qkv + (rowbase + q0 + qt*16 + m16) * QKVN + h * DHEAD;
    qf[qt][0] = *(const bf16x8*)(qrow + quad*8);
    qf[qt][1] = *(const bf16x8*)(qrow + 32 + quad*8);
  }

  f32x4 o[2][4] = {};   // O^T tiles [qt][dt], C-layout: row=d=quad*4+r, col=q=m16
  f32x4 o4[2]   = {};   // l-tile: ones-row MFMA accumulator; sum at quad==0, r==0

  // preload chunk 0
  uint4 kreg0 = *(const uint4*)(kgbase);
  uint4 kreg1 = *(const uint4*)(kgbase + (size_t)32 * QKVN);
  uint4 vreg0 = *(const uint4*)(vgbase);
  uint4 vreg1 = *(const uint4*)(vgbase + 32 * SEQ);

  for (int kv0 = 0; kv0 < SEQ; kv0 += 64) {
    __syncthreads();                         // prev chunk's readers done
    *(uint4*)(Ks + (srow     )*72 + scol) = kreg0;
    *(uint4*)(Ks + (srow + 32)*72 + scol) = kreg1;
    *(uint4*)(Vs + (srow     )*72 + scol) = vreg0;
    *(uint4*)(Vs + (srow + 32)*72 + scol) = vreg1;
    __syncthreads();                         // staging (+ ones-tile) visible

    // issue NEXT chunk's global loads now (latency hidden behind this chunk)
    const int kvn = (kv0 + 64) & (SEQ - 1);
    kreg0 = *(const uint4*)(kgbase + (size_t)(kvn     ) * QKVN);
    kreg1 = *(const uint4*)(kgbase + (size_t)(kvn + 32) * QKVN);
    vreg0 = *(const uint4*)(vgbase + kvn);
    vreg1 = *(const uint4*)(vgbase + 32 * SEQ + kvn);

    // ---- S^T = K Q^T for all 64 kv; p = exp2(s); P -> per-wave LDS ----
    // Both halves before ONE drain: QK(kh=1) MFMAs overlap exp(kh=0) VALU.
#pragma unroll
    for (int kh = 0; kh < 2; kh++) {
#pragma unroll
      for (int t2 = 0; t2 < 2; t2++) {
        const int t = kh*2 + t2;
        const bf16x8 kf0 = *(const bf16x8*)(Ks + (t*16 + m16)*72 + quad*8);
        const bf16x8 kf1 = *(const bf16x8*)(Ks + (t*16 + m16)*72 + 32 + quad*8);
#pragma unroll
        for (int qt = 0; qt < 2; qt++) {
          f32x4 s = {};
          s = __builtin_amdgcn_mfma_f32_16x16x32_bf16(kf0, qf[qt][0], s, 0, 0, 0);
          s = __builtin_amdgcn_mfma_f32_16x16x32_bf16(kf1, qf[qt][1], s, 0, 0, 0);
          float p[4];
#pragma unroll
          for (int r = 0; r < 4; r++)
            p[r] = __builtin_amdgcn_exp2f(s[r]);   // kv=t*16+quad*4+r, q=m16
          *(uint2*)(pb + (qt*16 + m16)*72 + kh*32 + t2*16 + quad*4) =
              make_uint2(pack_bf16(p[0], p[1]), pack_bf16(p[2], p[3]));
        }
      }
    }
    asm volatile("s_waitcnt lgkmcnt(0)" ::: "memory");  // wave-internal P RAW

    // ---- O^T += V^T P^T, both 32-kv halves; l via ones-row MFMA ----
#pragma unroll
    for (int kh = 0; kh < 2; kh++) {
      bf16x8 pf[2], vf[4], vf4;
#pragma unroll
      for (int qt = 0; qt < 2; qt++)
        pf[qt] = *(const bf16x8*)(pb + (qt*16 + m16)*72 + kh*32 + quad*8);
#pragma unroll
      for (int dt = 0; dt < 4; dt++)
        vf[dt] = *(const bf16x8*)(Vs + (dt*16 + m16)*72 + kh*32 + quad*8);
      vf4 = *(const bf16x8*)(Vs + (64 + m16)*72 + kh*32 + quad*8);
      __builtin_amdgcn_s_setprio(1);
#pragma unroll
      for (int qt = 0; qt < 2; qt++) {
#pragma unroll
        for (int dt = 0; dt < 4; dt++)
          o[qt][dt] = __builtin_amdgcn_mfma_f32_16x16x32_bf16(vf[dt], pf[qt], o[qt][dt], 0, 0, 0);
        o4[qt] = __builtin_amdgcn_mfma_f32_16x16x32_bf16(vf4, pf[qt], o4[qt], 0, 0, 0);
      }
      __builtin_amdgcn_s_setprio(0);
    }
  }

  // ---- epilogue: l = o4[qt][0] at lane m16 (quad 0, r 0); broadcast, divide ----
#pragma unroll
  for (int qt = 0; qt < 2; qt++) {
    const float l = __shfl(o4[qt][0], m16, 64);  // every lane reads its q=m16 sum
    const float inv = 1.0f / l;
    const size_t row = rowbase + q0 + qt*16 + m16;     // q = m16
#pragma unroll
    for (int dt = 0; dt < 4; dt++) {
      ushort4 st;
      st.x = f2bf(o[qt][dt][0] * inv);
      st.y = f2bf(o[qt][dt][1] * inv);
      st.z = f2bf(o[qt][dt][2] * inv);
      st.w = f2bf(o[qt][dt][3] * inv);
      *(ushort4*)(attn_out + row*MODELD + h*DHEAD + dt*16 + quad*4) = st;
    }
  }
}

// ---------------- launch ----------------
extern "C" void kernel_launch(void* const* d_in, const int* in_sizes, int n_in,
                              void* d_out, int out_size, void* d_ws, size_t ws_size,
                              hipStream_t stream) {
  // Reference dtypes: ALL inputs fp32, output fp32.
  const float* x     = (const float*)d_in[0];
  const float* w_q   = (const float*)d_in[1];
  const float* w_kv  = (const float*)d_in[2];
  const float* w_out = (const float*)d_in[3];
  const float* b_out = (const float*)d_in[4];

  ushort* wqkvT = (ushort*)d_ws;                         // 1152 x 1024 bf16
  ushort* woutT = wqkvT + (size_t)QKVN * MODELD;         // 1024 x 1024 bf16
  ushort* xb    = woutT + (size_t)MODELD * MODELD;       // 8192 x 1024 bf16
  ushort* qkv   = xb    + (size_t)MROWS * MODELD;        // 8192 x 1152 bf16
  ushort* attn  = qkv   + (size_t)MROWS * QKVN;          // 8192 x 1024 bf16
  ushort* vTb   = attn  + (size_t)MROWS * MODELD;        // 4 x 64 x 2048 bf16 (V^T)
  // total ws use ~59 MB

  // fused prep: x->bf16 + 3 weight transposes (scale folded into w_q)
  prep<<<10368, 256, 0, stream>>>(x, w_q, w_kv, w_out, xb, wqkvT, woutT);

  // fused QKV projection: (8192x1024) @ (1152x1024)^T -> 8192x1152 bf16 (+ V^T side-write)
  gemm_bt<false><<<dim3(QKVN/128, MROWS/128), 256, 0, stream>>>(
      xb, wqkvT, (void*)qkv, nullptr, vTb, MODELD, MODELD, MODELD, QKVN);

  // flash MQA -> attn (8192 x 1024 bf16, col = h*64+d)
  mqa_attn<<<dim3(SEQ/128, NHEADS, NBATCH), 256, 0, stream>>>(qkv, vTb, attn);

  // output projection + bias -> d_out (fp32)
  gemm_bt<true><<<dim3(MODELD/128, MROWS/128), 256, 0, stream>>>(
      attn, woutT, d_out, b_out, nullptr, MODELD, MODELD, MODELD, MODELD);
}

// Round 7
// 235.097 us; speedup vs baseline: 1.1406x; 1.0572x over previous
//
#include <hip/hip_runtime.h>
#include <hip/hip_bf16.h>
#include <stdint.h>

#define SEQ    2048
#define NBATCH 4
#define NHEADS 16
#define DHEAD  64
#define MODELD 1024
#define QKVN   1152          // 1024 q + 64 k + 64 v columns
#define MROWS  (NBATCH*SEQ)  // 8192
// exp(s*0.125) == exp2(s * 0.125 * log2(e)); folded into w_q at transpose time
#define SCALE_LOG2E 0.1803368801111244f

typedef __bf16 bf16x8 __attribute__((ext_vector_type(8)));
typedef float  f32x4  __attribute__((ext_vector_type(4)));

typedef __attribute__((address_space(1))) void* as1_void_p;
typedef __attribute__((address_space(3))) void* as3_void_p;

__device__ __forceinline__ void gld_lds16(const void* g, void* l) {
  __builtin_amdgcn_global_load_lds((as1_void_p)(g), (as3_void_p)(l), 16, 0, 0);
}

__device__ __forceinline__ ushort f2bf(float f) {
  union { float f; uint32_t i; } t; t.f = f;
  uint32_t r = (t.i + 0x7fffu + ((t.i >> 16) & 1u)) >> 16;
  return (ushort)r;
}
__device__ __forceinline__ uint32_t pack_bf16(float a, float b) {
  union { __hip_bfloat162 h2; uint32_t u; } cv;
  cv.h2 = __float22bfloat162_rn(make_float2(a, b));
  return cv.u;
}

// ---------------- fused prep: x convert + 3 weight transposes ----------------
// flat grid: [0,8192) x-convert; [8192,9216) w_q^T; [9216,9344) w_kv^T; [9344,10368) w_out^T
__device__ __forceinline__ void do_transpose(const float* __restrict__ src,
                                             ushort* __restrict__ dst,
                                             int R, int C, float scale,
                                             int gx, int gy, int tid) {
  __shared__ float tile[32][33];
  const int tx = tid & 31, ty = tid >> 5;  // ty in 0..7
  const int c0 = gx * 32, r0 = gy * 32;
#pragma unroll
  for (int j = 0; j < 4; j++)
    tile[ty*4 + j][tx] = src[(size_t)(r0 + ty*4 + j) * C + c0 + tx];
  __syncthreads();
#pragma unroll
  for (int j = 0; j < 4; j++)
    dst[(size_t)(c0 + ty*4 + j) * R + r0 + tx] = f2bf(tile[tx][ty*4 + j] * scale);
}

__global__ __launch_bounds__(256)
void prep(const float* __restrict__ x, const float* __restrict__ w_q,
          const float* __restrict__ w_kv, const float* __restrict__ w_out,
          ushort* __restrict__ xb, ushort* __restrict__ wqkvT,
          ushort* __restrict__ woutT) {
  const int bid = blockIdx.x, tid = threadIdx.x;
  if (bid < 8192) {                      // x -> bf16, 1024 elems/block
    const size_t i = ((size_t)bid * 256 + tid) * 4;
    const float4 v = *(const float4*)(x + i);
    ushort4 o;
    o.x = f2bf(v.x); o.y = f2bf(v.y); o.z = f2bf(v.z); o.w = f2bf(v.w);
    *(ushort4*)(xb + i) = o;
  } else if (bid < 9216) {               // w_q^T (scale folded)
    const int t = bid - 8192;
    do_transpose(w_q, wqkvT, MODELD, MODELD, SCALE_LOG2E, t & 31, t >> 5, tid);
  } else if (bid < 9344) {               // w_kv^T -> rows 1024..1151
    const int t = bid - 9216;
    do_transpose(w_kv, wqkvT + (size_t)MODELD * MODELD, MODELD, 128, 1.0f,
                 t & 3, t >> 2, tid);
  } else {                               // w_out^T
    const int t = bid - 9344;
    do_transpose(w_out, woutT, MODELD, MODELD, 1.0f, t & 31, t >> 5, tid);
  }
}

// ---------------- GEMM: C(MxN) = A(MxK) * Bt(NxK)^T  (+bias), bf16 in --------
// R5 (verified R6: -8us): BK=64 — halves barrier-drain count, 32-MFMA clusters.
// Rule-#21 both-sides XOR involution on the 128B LDS rows: linear LDS dest
// (gld_lds), global SOURCE granule pre-XOR'd with row&7, fragment reads XOR'd
// the same. MFMA accumulation order bit-identical to BK=32.
// T1 (m204): bijective XCD-aware tile remap (R4: ~-3..5us).
// VT!=nullptr: additionally write cols 1088..1151 transposed as vT[b][d][n].
template <bool OUT_F32>
__global__ __launch_bounds__(256)
void gemm_bt(const ushort* __restrict__ A, const ushort* __restrict__ Bt,
             void* __restrict__ Cp, const float* __restrict__ bias,
             ushort* __restrict__ VT,
             int K, int lda, int ldb, int ldc) {
  __shared__ __attribute__((aligned(16))) ushort As[128*64];
  __shared__ __attribute__((aligned(16))) ushort Bs[128*64];
  const int tid = threadIdx.x;
  const int w = tid >> 6, lane = tid & 63;
  const int quad = lane >> 4, m16 = lane & 15;

  // bijective XCD swizzle (m204): phys id -> contiguous logical chunk per XCD
  const int nwg = gridDim.x * gridDim.y;
  const int orig = blockIdx.y * gridDim.x + blockIdx.x;
  const int qq = nwg >> 3, rr = nwg & 7;
  const int xcd = orig & 7, loc = orig >> 3;
  const int L = (xcd < rr ? xcd * (qq + 1) : rr * (qq + 1) + (xcd - rr) * qq) + loc;
  const int bm0 = (L / gridDim.x) * 128, bn0 = (L % gridDim.x) * 128;

  f32x4 acc[4][4] = {};

  // staging map: lane covers (row = w*32 + c*8 + (lane>>3), granule = lane&7),
  // 4 calls (c=0..3) per matrix. Source granule XOR'd (involution).
  const int sr = lane >> 3;                       // 0..7
  const int sg = ((lane & 7) ^ (sr & 7)) * 8;     // pre-swizzled source col
  const ushort* Ag = A  + (size_t)(bm0 + w*32 + sr) * lda + sg;
  const ushort* Bg = Bt + (size_t)(bn0 + w*32 + sr) * ldb + sg;
  ushort* AsW = As + (w*32)*64;   // wave-uniform base; HW adds lane*16B
  ushort* BsW = Bs + (w*32)*64;
  const int wm = (w >> 1) * 64, wn = (w & 1) * 64;

  for (int kb = 0; kb < K; kb += 64) {
#pragma unroll
    for (int c = 0; c < 4; c++) {
      gld_lds16(Ag + (size_t)(c*8)*lda + kb, AsW + c*8*64);
      gld_lds16(Bg + (size_t)(c*8)*ldb + kb, BsW + c*8*64);
    }
    __syncthreads();
#pragma unroll
    for (int kk = 0; kk < 2; kk++) {
      bf16x8 af[4], bfr[4];
      const int rg = ((kk*4 + quad) ^ (m16 & 7)) * 8;  // swizzled read granule
#pragma unroll
      for (int mi = 0; mi < 4; mi++)
        af[mi] = *(const bf16x8*)(As + (wm + mi*16 + m16)*64 + rg);
#pragma unroll
      for (int ni = 0; ni < 4; ni++)
        bfr[ni] = *(const bf16x8*)(Bs + (wn + ni*16 + m16)*64 + rg);
#pragma unroll
      for (int mi = 0; mi < 4; mi++)
#pragma unroll
        for (int ni = 0; ni < 4; ni++)
          acc[mi][ni] = __builtin_amdgcn_mfma_f32_16x16x32_bf16(
              af[mi], bfr[ni], acc[mi][ni], 0, 0, 0);
    }
    __syncthreads();
  }

  // epilogue: C/D layout col=lane&15, row=quad*4+reg
  const bool blockHasV = (VT != nullptr) && (bn0 + 128 > 1088);
#pragma unroll
  for (int ni = 0; ni < 4; ni++) {
    const int col = bn0 + wn + ni*16 + m16;
    const float bv = bias ? bias[col] : 0.0f;
#pragma unroll
    for (int mi = 0; mi < 4; mi++) {
#pragma unroll
      for (int r = 0; r < 4; r++) {
        const int row = bm0 + wm + mi*16 + quad*4 + r;
        const float v = acc[mi][ni][r] + bv;
        if (OUT_F32) ((float*)Cp)[(size_t)row*ldc + col] = v;
        else         ((ushort*)Cp)[(size_t)row*ldc + col] = f2bf(v);
        if (blockHasV && col >= 1088) {  // V columns -> transposed copy
          const int d = col - 1088, bb = row >> 11, n = row & 2047;
          VT[((size_t)bb * DHEAD + d) * SEQ + n] = f2bf(v);
        }
      }
    }
  }
}

// ---------------- Flash MQA attention, v9: 2 heads/block ----------------
// MQA: all heads share K/V. v7 staged the same K/V tile 16x (once per head).
// v9: 512 threads = 8 waves; waves 0-3 -> head 2y, waves 4-7 -> head 2y+1,
// SAME Ks/Vs staging (per-thread staging halves: 1 K-row + 1 V-row granule
// per chunk). Grid 1024 -> 512 blocks = exactly 2/CU; 16 waves/CU (was ~10).
// Per-wave compute body identical to v7 (R4/R6-verified): ones-row l-MFMA,
// single lgkmcnt(0) drain per chunk, setprio around PV.
// LDS 57.6 KB (Ks 9.2K + Vs 11.5K + pbuf[8] 36.9K) -> 2 blocks/CU.
__global__ __launch_bounds__(512, 2)
void mqa_attn(const ushort* __restrict__ qkv, const ushort* __restrict__ vT,
              ushort* __restrict__ attn_out) {
  __shared__ __attribute__((aligned(16))) ushort Ks[64*72];      // K[kv][d], pad 72
  __shared__ __attribute__((aligned(16))) ushort Vs[80*72];      // V^T[d][kv]; rows 64..79 = ones-tile
  __shared__ __attribute__((aligned(16))) ushort pbuf[8][32*72]; // per-wave P[q(32)][64kv], pad 72

  const int tid = threadIdx.x;
  const int w = tid >> 6, lane = tid & 63;
  const int quad = lane >> 4, m16 = lane & 15;
  const int h = blockIdx.y * 2 + (w >> 2);           // 2 heads per block
  const int b = blockIdx.z;
  const size_t rowbase = (size_t)b * SEQ;
  const int q0 = blockIdx.x * 128 + (w & 3) * 32;    // 4 waves cover 128 q-rows/head
  const ushort* vTb = vT + (size_t)b * DHEAD * SEQ;
  ushort* pb = pbuf[w];

  // ones-tile init (once): Vs row 64 = 1.0 (bf16 0x3F80), rows 65..79 = 0.
  for (int i = tid; i < 16*72; i += 512)
    Vs[64*72 + i] = (i < 72) ? (ushort)0x3F80 : (ushort)0;

  // staging map: 512 threads cover the full 64x64 tile in ONE pass:
  // thread -> (row = tid>>3 in 0..63, col granule = (tid&7)*8)
  const int srow = tid >> 3, scol = (tid & 7) * 8;
  const ushort* kgbase = qkv + (rowbase + srow) * QKVN + 1024 + scol;
  const ushort* vgbase = vTb + (size_t)srow * SEQ + scol;

  // persistent Q fragments (B-layout: n=q=m16, k=d=quad*8 (+32)); q pre-scaled
  bf16x8 qf[2][2];
#pragma unroll
  for (int qt = 0; qt < 2; qt++) {
    const ushort* qrow = qkv + (rowbase + q0 + qt*16 + m16) * QKVN + h * DHEAD;
    qf[qt][0] = *(const bf16x8*)(qrow + quad*8);
    qf[qt][1] = *(const bf16x8*)(qrow + 32 + quad*8);
  }

  f32x4 o[2][4] = {};   // O^T tiles [qt][dt], C-layout: row=d=quad*4+r, col=q=m16
  f32x4 o4[2]   = {};   // l-tile: ones-row MFMA accumulator; sum at quad==0, r==0

  // preload chunk 0
  uint4 kreg = *(const uint4*)(kgbase);
  uint4 vreg = *(const uint4*)(vgbase);

  for (int kv0 = 0; kv0 < SEQ; kv0 += 64) {
    __syncthreads();                         // prev chunk's readers done
    *(uint4*)(Ks + srow*72 + scol) = kreg;
    *(uint4*)(Vs + srow*72 + scol) = vreg;
    __syncthreads();                         // staging (+ ones-tile) visible

    // issue NEXT chunk's global loads now (latency hidden behind this chunk)
    const int kvn = (kv0 + 64) & (SEQ - 1);
    kreg = *(const uint4*)(kgbase + (size_t)kvn * QKVN);
    vreg = *(const uint4*)(vgbase + kvn);

    // ---- S^T = K Q^T for all 64 kv; p = exp2(s); P -> per-wave LDS ----
    // Both halves before ONE drain: QK(kh=1) MFMAs overlap exp(kh=0) VALU.
#pragma unroll
    for (int kh = 0; kh < 2; kh++) {
#pragma unroll
      for (int t2 = 0; t2 < 2; t2++) {
        const int t = kh*2 + t2;
        const bf16x8 kf0 = *(const bf16x8*)(Ks + (t*16 + m16)*72 + quad*8);
        const bf16x8 kf1 = *(const bf16x8*)(Ks + (t*16 + m16)*72 + 32 + quad*8);
#pragma unroll
        for (int qt = 0; qt < 2; qt++) {
          f32x4 s = {};
          s = __builtin_amdgcn_mfma_f32_16x16x32_bf16(kf0, qf[qt][0], s, 0, 0, 0);
          s = __builtin_amdgcn_mfma_f32_16x16x32_bf16(kf1, qf[qt][1], s, 0, 0, 0);
          float p[4];
#pragma unroll
          for (int r = 0; r < 4; r++)
            p[r] = __builtin_amdgcn_exp2f(s[r]);   // kv=t*16+quad*4+r, q=m16
          *(uint2*)(pb + (qt*16 + m16)*72 + kh*32 + t2*16 + quad*4) =
              make_uint2(pack_bf16(p[0], p[1]), pack_bf16(p[2], p[3]));
        }
      }
    }
    asm volatile("s_waitcnt lgkmcnt(0)" ::: "memory");  // wave-internal P RAW

    // ---- O^T += V^T P^T, both 32-kv halves; l via ones-row MFMA ----
#pragma unroll
    for (int kh = 0; kh < 2; kh++) {
      bf16x8 pf[2], vf[4], vf4;
#pragma unroll
      for (int qt = 0; qt < 2; qt++)
        pf[qt] = *(const bf16x8*)(pb + (qt*16 + m16)*72 + kh*32 + quad*8);
#pragma unroll
      for (int dt = 0; dt < 4; dt++)
        vf[dt] = *(const bf16x8*)(Vs + (dt*16 + m16)*72 + kh*32 + quad*8);
      vf4 = *(const bf16x8*)(Vs + (64 + m16)*72 + kh*32 + quad*8);
      __builtin_amdgcn_s_setprio(1);
#pragma unroll
      for (int qt = 0; qt < 2; qt++) {
#pragma unroll
        for (int dt = 0; dt < 4; dt++)
          o[qt][dt] = __builtin_amdgcn_mfma_f32_16x16x32_bf16(vf[dt], pf[qt], o[qt][dt], 0, 0, 0);
        o4[qt] = __builtin_amdgcn_mfma_f32_16x16x32_bf16(vf4, pf[qt], o4[qt], 0, 0, 0);
      }
      __builtin_amdgcn_s_setprio(0);
    }
  }

  // ---- epilogue: l = o4[qt][0] at lane m16 (quad 0, r 0); broadcast, divide ----
#pragma unroll
  for (int qt = 0; qt < 2; qt++) {
    const float l = __shfl(o4[qt][0], m16, 64);  // every lane reads its q=m16 sum
    const float inv = 1.0f / l;
    const size_t row = rowbase + q0 + qt*16 + m16;     // q = m16
#pragma unroll
    for (int dt = 0; dt < 4; dt++) {
      ushort4 st;
      st.x = f2bf(o[qt][dt][0] * inv);
      st.y = f2bf(o[qt][dt][1] * inv);
      st.z = f2bf(o[qt][dt][2] * inv);
      st.w = f2bf(o[qt][dt][3] * inv);
      *(ushort4*)(attn_out + row*MODELD + h*DHEAD + dt*16 + quad*4) = st;
    }
  }
}

// ---------------- launch ----------------
extern "C" void kernel_launch(void* const* d_in, const int* in_sizes, int n_in,
                              void* d_out, int out_size, void* d_ws, size_t ws_size,
                              hipStream_t stream) {
  // Reference dtypes: ALL inputs fp32, output fp32.
  const float* x     = (const float*)d_in[0];
  const float* w_q   = (const float*)d_in[1];
  const float* w_kv  = (const float*)d_in[2];
  const float* w_out = (const float*)d_in[3];
  const float* b_out = (const float*)d_in[4];

  ushort* wqkvT = (ushort*)d_ws;                         // 1152 x 1024 bf16
  ushort* woutT = wqkvT + (size_t)QKVN * MODELD;         // 1024 x 1024 bf16
  ushort* xb    = woutT + (size_t)MODELD * MODELD;       // 8192 x 1024 bf16
  ushort* qkv   = xb    + (size_t)MROWS * MODELD;        // 8192 x 1152 bf16
  ushort* attn  = qkv   + (size_t)MROWS * QKVN;          // 8192 x 1024 bf16
  ushort* vTb   = attn  + (size_t)MROWS * MODELD;        // 4 x 64 x 2048 bf16 (V^T)
  // total ws use ~59 MB

  // fused prep: x->bf16 + 3 weight transposes (scale folded into w_q)
  prep<<<10368, 256, 0, stream>>>(x, w_q, w_kv, w_out, xb, wqkvT, woutT);

  // fused QKV projection: (8192x1024) @ (1152x1024)^T -> 8192x1152 bf16 (+ V^T side-write)
  gemm_bt<false><<<dim3(QKVN/128, MROWS/128), 256, 0, stream>>>(
      xb, wqkvT, (void*)qkv, nullptr, vTb, MODELD, MODELD, MODELD, QKVN);

  // flash MQA -> attn (8192 x 1024 bf16, col = h*64+d); 2 heads/block
  mqa_attn<<<dim3(SEQ/128, NHEADS/2, NBATCH), 512, 0, stream>>>(qkv, vTb, attn);

  // output projection + bias -> d_out (fp32)
  gemm_bt<true><<<dim3(MODELD/128, MROWS/128), 256, 0, stream>>>(
      attn, woutT, d_out, b_out, nullptr, MODELD, MODELD, MODELD, MODELD);
}